// Round 1
// baseline (287.737 us; speedup 1.0000x reference)
//
#include <hip/hip_runtime.h>

// SoftDecisionTree (R7): gemm1 restaged — A converted to bf16 in registers
// (once per element) with reg double-buffered prefetch issued after the
// pre-compute barrier; B double-buffered in LDS so steady-state barriers
// drain nothing. Inner loop is pure ds_read_b128 + MFMA.
//   prep : Wb=bf16(W) padded, dT=softmax(leaf_params)^T
//   part = xs @ Wb^T (split-K=4, fp16 partials)    gemm1_kernel
//   lf   = tree(sigmoid(sum_s part + b))           reduce_tree_kernel (bf16 out)
//   out  = lf @ dT^T                               gemm2_kernel

typedef __bf16 bf16x8 __attribute__((ext_vector_type(8)));
typedef float f32x4 __attribute__((ext_vector_type(4)));
typedef _Float16 f16x8 __attribute__((ext_vector_type(8)));

#define B_DIM 8192
#define F_DIM 4096
#define NI 511
#define NL 512
#define K_DIM 1000
#define KPAD 1024
#define SPLIT 4
#define KCHUNK 1024

#define W_BLKS  1024    // 512*4096 / (256*8)
#define SM_BLKS 512

// RNE fp32->bf16 (prep / tree outputs)
__device__ inline unsigned short f2bf(float f) {
    unsigned int u = __float_as_uint(f);
    return (unsigned short)((u + 0x7FFFu + ((u >> 16) & 1u)) >> 16);
}
__device__ inline unsigned int pk_bf16(float a, float b) {
    return (unsigned int)f2bf(a) | ((unsigned int)f2bf(b) << 16);
}
// cheap round-half-up fp32 pair -> packed bf16x2 (2 adds + 1 perm)
__device__ inline unsigned int pk2_hu(float a, float b) {
    unsigned int ua = __float_as_uint(a) + 0x8000u;
    unsigned int ub = __float_as_uint(b) + 0x8000u;
    return __builtin_amdgcn_perm(ub, ua, 0x07060302u);
}

// async global->LDS, 16 B/lane; LDS dest = wave-uniform base + lane*16
typedef __attribute__((address_space(1))) const unsigned int guint;
typedef __attribute__((address_space(3))) unsigned int luint;
__device__ inline void gload16(const unsigned short* g, unsigned short* l) {
    __builtin_amdgcn_global_load_lds((guint*)g, (luint*)l, 16, 0, 0);
}

// swizzled bf16 fragment load: granule(16B) index ^= row&7  -> conflict-free
__device__ inline bf16x8 ldb(const unsigned short* Lbase, int r, int kb) {
    const int g = (kb >> 3) ^ (r & 7);
    return *(const bf16x8*)&Lbase[r * 64 + g * 8];
}

__device__ inline float waveMax(float v) {
#pragma unroll
    for (int off = 32; off; off >>= 1) v = fmaxf(v, __shfl_down(v, off, 64));
    return v;
}
__device__ inline float waveSum(float v) {
#pragma unroll
    for (int off = 32; off; off >>= 1) v += __shfl_down(v, off, 64);
    return v;
}

// ---------------- prep: W->bf16 (512-row pad), softmax^T ----------------
__global__ __launch_bounds__(256) void prep_kernel(
    const float* __restrict__ W, unsigned short* __restrict__ Wb,
    const float* __restrict__ lp, unsigned short* __restrict__ dT)
{
    __shared__ float sred[8];
    const int bid = blockIdx.x;
    const int tid = threadIdx.x;

    if (bid < W_BLKS) {
        const size_t i = ((size_t)bid * 256 + tid) * 8;
        const int row = (int)(i >> 12);  // /4096
        uint4 h = {0u, 0u, 0u, 0u};
        if (row < NI) {
            const float4 a = *(const float4*)(W + i);
            const float4 b = *(const float4*)(W + i + 4);
            h.x = pk_bf16(a.x, a.y);
            h.y = pk_bf16(a.z, a.w);
            h.z = pk_bf16(b.x, b.y);
            h.w = pk_bf16(b.z, b.w);
        }
        *(uint4*)(Wb + i) = h;
        return;
    }
    // softmax + transpose: dT[n][k] = softmax(leaf_params[k])[n]
    const int k = bid - W_BLKS;
    const int lane = tid & 63;
    const int wave = tid >> 6;
    const float* rowp = lp + (size_t)k * K_DIM;

    float vals[4];
    float mx = -3.0e38f;
#pragma unroll
    for (int c = 0; c < 4; ++c) {
        const int n = tid + c * 256;
        vals[c] = (n < K_DIM) ? rowp[n] : -3.0e38f;
        mx = fmaxf(mx, vals[c]);
    }
    mx = waveMax(mx);
    if (lane == 0) sred[wave] = mx;
    __syncthreads();
    const float gmax = fmaxf(fmaxf(sred[0], sred[1]), fmaxf(sred[2], sred[3]));

    float sum = 0.f;
#pragma unroll
    for (int c = 0; c < 4; ++c) {
        const int n = tid + c * 256;
        const float e = (n < K_DIM) ? __expf(vals[c] - gmax) : 0.f;
        vals[c] = e;
        sum += e;
    }
    sum = waveSum(sum);
    if (lane == 0) sred[4 + wave] = sum;
    __syncthreads();
    const float inv = 1.0f / (sred[4] + sred[5] + sred[6] + sred[7]);
#pragma unroll
    for (int c = 0; c < 4; ++c) {
        const int n = tid + c * 256;
        if (n < K_DIM) dT[(size_t)n * NL + k] = f2bf(vals[c] * inv);
    }
}

// ---------------- GEMM1: part[z] = xs @ Wb^T ----------------
// grid 1024 = 8 xcd x 8 mhi x 4 z x 4 nt; m-rows partitioned per XCD.
// A: fp32 global -> regs (prefetch t+1 during compute t) -> cvt bf16 -> LDS.
// B: global_load_lds, double-buffered (prefetch t+1 during compute t).
// Steady state: no vmem pending at the pre-compute barrier.
__global__ __launch_bounds__(256) void gemm1_kernel(
    const float* __restrict__ A, const unsigned short* __restrict__ Bb,
    _Float16* __restrict__ part)
{
    __shared__ __align__(16) unsigned short Al[128 * 64];        // 16 KB bf16
    __shared__ __align__(16) unsigned short Bl[2][128 * 64];     // 32 KB bf16 dbuf

    const int id = blockIdx.x;
    const int xcd = id & 7;
    const int jj = (id >> 3) & 15;
    const int mhi = id >> 7;
    const int z = jj >> 2;
    const int nt = jj & 3;
    const int m0 = (mhi * 8 + xcd) * 128;
    const int n0 = nt * 128;
    const int kbeg = z * KCHUNK;

    const int tid = threadIdx.x;
    const int lane = tid & 63;
    const int wave = tid >> 6;
    const int wm = (wave >> 1) * 64;
    const int wn = (wave & 1) * 64;
    const int quad = lane >> 4;
    const int l16 = lane & 15;

    // A reg staging: pass p covers row = wave*4 + (lane>>4) + p*16; lane&15 = q
    // covers source cols [q*4, q*4+4). Global: 16 lanes x 16 B = 256 B contiguous.
    // LDS write: granule g=q>>1 (cols 8g..8g+7) stored at (g ^ (r&7)); half q&1.
    const int rowA = wave * 4 + (lane >> 4);
    const int q = lane & 15;
    const float* gA = A + (size_t)(m0 + rowA) * F_DIM + kbeg + q * 4;

    // B staging (gload_lds): pass p covers rows p*32 + wave*8 + (lane>>3);
    // granule-of-8 = (lane&7) ^ dr  [matches ldb swizzle]
    const int drb = lane >> 3;
    const int cb = ((lane & 7) ^ drb) * 8;
    const unsigned short* gB = Bb + (size_t)(n0 + wave * 8 + drb) * F_DIM + kbeg + cb;
    const int lBoff = wave * 8 * 64;

    const f32x4 zero = {0.f, 0.f, 0.f, 0.f};
    f32x4 acc[4][4];
#pragma unroll
    for (int i = 0; i < 4; ++i)
#pragma unroll
        for (int j2 = 0; j2 < 4; ++j2) acc[i][j2] = zero;

    // prologue: issue B(0) async and A(0) reg loads
#pragma unroll
    for (int p = 0; p < 4; ++p)
        gload16(gB + (size_t)p * 32 * F_DIM, &Bl[0][lBoff + p * 2048]);
    f32x4 ab[2][8];
#pragma unroll
    for (int p = 0; p < 8; ++p)
        ab[0][p] = *(const f32x4*)(gA + (size_t)p * 16 * F_DIM);

#pragma unroll
    for (int t = 0; t < 16; ++t) {
        // stage A(t): cvt once per element, swizzled ds_write_b64
#pragma unroll
        for (int p = 0; p < 8; ++p) {
            const int r = rowA + p * 16;
            uint2 w;
            w.x = pk2_hu(ab[t & 1][p].x, ab[t & 1][p].y);
            w.y = pk2_hu(ab[t & 1][p].z, ab[t & 1][p].w);
            *(uint2*)&Al[r * 64 + (((q >> 1) ^ (r & 7)) * 8) + (q & 1) * 4] = w;
        }
        __syncthreads();  // drains B(t) vmem (in flight since iter t-1) + lgkm writes

        // prefetch t+1: issued before compute so the end barrier's drain overlaps it
        if (t < 15) {
#pragma unroll
            for (int p = 0; p < 8; ++p)
                ab[(t + 1) & 1][p] =
                    *(const f32x4*)(gA + (size_t)(t + 1) * 64 + (size_t)p * 16 * F_DIM);
#pragma unroll
            for (int p = 0; p < 4; ++p)
                gload16(gB + (size_t)(t + 1) * 64 + (size_t)p * 32 * F_DIM,
                        &Bl[(t + 1) & 1][lBoff + p * 2048]);
        }

        // compute tile t: pure ds_read_b128 + MFMA
#pragma unroll
        for (int kk = 0; kk < 64; kk += 32) {
            const int kb = kk + quad * 8;
            bf16x8 av[4], bv[4];
#pragma unroll
            for (int i = 0; i < 4; ++i)
                av[i] = ldb(Al, wm + i * 16 + l16, kb);
#pragma unroll
            for (int j2 = 0; j2 < 4; ++j2)
                bv[j2] = ldb(&Bl[t & 1][0], wn + j2 * 16 + l16, kb);
#pragma unroll
            for (int i = 0; i < 4; ++i)
#pragma unroll
                for (int j2 = 0; j2 < 4; ++j2)
                    acc[i][j2] = __builtin_amdgcn_mfma_f32_16x16x32_bf16(av[i], bv[j2], acc[i][j2], 0, 0, 0);
        }
        __syncthreads();  // all waves done reading; drains t+1 prefetch under/after compute
    }

    _Float16* dst = part + (size_t)z * ((size_t)B_DIM * NL);
#pragma unroll
    for (int i = 0; i < 4; ++i) {
        const int mbase = m0 + wm + i * 16 + quad * 4;
#pragma unroll
        for (int j2 = 0; j2 < 4; ++j2) {
            const int n = n0 + wn + j2 * 16 + l16;
#pragma unroll
            for (int r = 0; r < 4; ++r)
                dst[(size_t)(mbase + r) * NL + n] = (_Float16)acc[i][j2][r];
        }
    }
}

// ---------------- fused reduce(fp16 partials) + bias + sigmoid + tree ----------------
__global__ __launch_bounds__(256) void reduce_tree_kernel(
    const _Float16* __restrict__ part, const float* __restrict__ bvec,
    unsigned short* __restrict__ leafbf)
{
    __shared__ float bsh[NL];
    __shared__ float prow[4][NL];

    const int tid = threadIdx.x;
    bsh[tid] = (tid < NI) ? bvec[tid] : 0.0f;
    const int t2 = tid + 256;
    bsh[t2] = (t2 < NI) ? bvec[t2] : 0.0f;

    const int wave = tid >> 6;
    const int lane = tid & 63;
    const int row = blockIdx.x * 4 + wave;
    const size_t base = (size_t)row * NL + lane * 8;

    float v[8] = {0.f, 0.f, 0.f, 0.f, 0.f, 0.f, 0.f, 0.f};
#pragma unroll
    for (int s = 0; s < SPLIT; ++s) {
        const f16x8 h = *(const f16x8*)(part + (size_t)s * ((size_t)B_DIM * NL) + base);
#pragma unroll
        for (int e = 0; e < 8; ++e) v[e] += (float)h[e];
    }
    __syncthreads();

#pragma unroll
    for (int i = 0; i < 8; ++i) {
        const float x = v[i] + bsh[lane * 8 + i];
        prow[wave][lane * 8 + i] = 1.0f / (1.0f + __expf(-x));
    }
    __syncthreads();

    const float* pr = prow[wave];
    float pre = 1.0f;
    int pnode = 0;
#pragma unroll
    for (int t = 5; t >= 0; --t) {
        const int bit = (lane >> t) & 1;
        const float p = pr[pnode];
        pre *= bit ? p : (1.0f - p);
        pnode = 2 * pnode + 1 + bit;
    }
    unsigned short outs[8];
#pragma unroll
    for (int jj = 0; jj < 8; ++jj) {
        float prob = pre;
        int node = pnode;
#pragma unroll
        for (int t = 2; t >= 0; --t) {
            const int bit = (jj >> t) & 1;
            const float p = pr[node];
            prob *= bit ? p : (1.0f - p);
            node = 2 * node + 1 + bit;
        }
        outs[jj] = f2bf(prob);
    }
    uint4 r;
    r.x = (unsigned int)outs[0] | ((unsigned int)outs[1] << 16);
    r.y = (unsigned int)outs[2] | ((unsigned int)outs[3] << 16);
    r.z = (unsigned int)outs[4] | ((unsigned int)outs[5] << 16);
    r.w = (unsigned int)outs[6] | ((unsigned int)outs[7] << 16);
    *(uint4*)(leafbf + (size_t)row * NL + lane * 8) = r;
}

// ---------------- GEMM2: out = leaf_prob @ dists ----------------
// grid 512 = 8 xcd x 8 mhi x 8 nt; swizzled LDS; masked fp32 stores at n>=1000.
__global__ __launch_bounds__(256) void gemm2_kernel(
    const unsigned short* __restrict__ A, const unsigned short* __restrict__ Bm,
    float* __restrict__ out)
{
    __shared__ __align__(16) unsigned short Al[128 * 64];
    __shared__ __align__(16) unsigned short Bl[128 * 64];

    const int id = blockIdx.x;
    const int xcd = id & 7;
    const int j = id >> 3;
    const int nt = j & 7;
    const int mhi = j >> 3;
    const int m0 = (mhi * 8 + xcd) * 128;
    const int n0 = nt * 128;

    const int tid = threadIdx.x;
    const int lane = tid & 63;
    const int wave = tid >> 6;
    const int wm = (wave >> 1) * 64;
    const int wn = (wave & 1) * 64;
    const int quad = lane >> 4;
    const int l16 = lane & 15;

    const int drb = lane >> 3;
    const int cb = ((lane & 7) ^ drb) * 8;
    const unsigned short* gA = A + (size_t)(m0 + wave * 8 + drb) * NL + cb;
    const unsigned short* gB = Bm + (size_t)(n0 + wave * 8 + drb) * NL + cb;
    unsigned short* lA = &Al[wave * 8 * 64];
    unsigned short* lB = &Bl[wave * 8 * 64];

    const f32x4 zero = {0.f, 0.f, 0.f, 0.f};
    f32x4 acc[4][4];
#pragma unroll
    for (int i = 0; i < 4; ++i)
#pragma unroll
        for (int j2 = 0; j2 < 4; ++j2) acc[i][j2] = zero;

    for (int k0 = 0; k0 < NL; k0 += 64) {
#pragma unroll
        for (int p = 0; p < 4; ++p) {
            gload16(gA + k0 + (size_t)p * 32 * NL, lA + p * 2048);
            gload16(gB + k0 + (size_t)p * 32 * NL, lB + p * 2048);
        }
        __syncthreads();
#pragma unroll
        for (int kk = 0; kk < 64; kk += 32) {
            const int kb = kk + quad * 8;
            bf16x8 av[4], bv[4];
#pragma unroll
            for (int i = 0; i < 4; ++i)
                av[i] = ldb(Al, wm + i * 16 + l16, kb);
#pragma unroll
            for (int j2 = 0; j2 < 4; ++j2)
                bv[j2] = ldb(Bl, wn + j2 * 16 + l16, kb);
#pragma unroll
            for (int i = 0; i < 4; ++i)
#pragma unroll
                for (int j2 = 0; j2 < 4; ++j2)
                    acc[i][j2] = __builtin_amdgcn_mfma_f32_16x16x32_bf16(av[i], bv[j2], acc[i][j2], 0, 0, 0);
        }
        __syncthreads();
    }

#pragma unroll
    for (int i = 0; i < 4; ++i) {
        const int mbase = m0 + wm + i * 16 + quad * 4;
#pragma unroll
        for (int j2 = 0; j2 < 4; ++j2) {
            const int n = n0 + wn + j2 * 16 + l16;
            if (n < K_DIM) {
#pragma unroll
                for (int r = 0; r < 4; ++r)
                    out[(size_t)(mbase + r) * K_DIM + n] = acc[i][j2][r];
            }
        }
    }
}

extern "C" void kernel_launch(void* const* d_in, const int* in_sizes, int n_in,
                              void* d_out, int out_size, void* d_ws, size_t ws_size,
                              hipStream_t stream) {
    const float* xs = (const float*)d_in[0];
    const float* W  = (const float*)d_in[1];
    const float* b  = (const float*)d_in[2];
    const float* lp = (const float*)d_in[3];
    float* out = (float*)d_out;

    const size_t partB = (size_t)B_DIM * NL * 2;   //  8 MiB per slice (fp16)
    const size_t leafB = (size_t)B_DIM * NL * 2;   //  8 MiB
    const size_t dTB   = (size_t)KPAD * NL * 2;    //  1 MiB

    char* ws = (char*)d_ws;
    _Float16* part = (_Float16*)ws;
    unsigned short* leafbf = (unsigned short*)(ws + SPLIT * partB);
    unsigned short* dT = (unsigned short*)(ws + SPLIT * partB + leafB);
    unsigned short* Wb = (unsigned short*)(ws + SPLIT * partB + leafB + dTB);
    (void)ws_size;  // needs ~45 MiB; harness provides 512 MiB

    hipLaunchKernelGGL(prep_kernel, dim3(W_BLKS + SM_BLKS), dim3(256), 0, stream,
                       W, Wb, lp, dT);
    hipLaunchKernelGGL(gemm1_kernel, dim3(8 * 8 * 4 * 4), dim3(256), 0, stream,
                       xs, Wb, part);
    hipLaunchKernelGGL(reduce_tree_kernel, dim3(B_DIM / 4), dim3(256), 0, stream,
                       part, b, leafbf);
    hipLaunchKernelGGL(gemm2_kernel, dim3(8 * 8 * 8), dim3(256), 0, stream,
                       leafbf, dT, out);
}

// Round 2
// 263.699 us; speedup vs baseline: 1.0912x; 1.0912x over previous
//
#include <hip/hip_runtime.h>

// SoftDecisionTree (R8): gemm1 rebuilt as a counted-vmcnt pipeline (T3/T4):
// raw s_barrier + s_waitcnt vmcnt(12) (never 0 in steady state), A reg-prefetch
// distance 2, B global_load_lds with 4 LDS buffers distance 2, split-K 4->2.
//   prep : Wb=bf16(W) padded, dT=softmax(leaf_params)^T
//   part = xs @ Wb^T (split-K=2, fp16 partials)    gemm1_kernel
//   lf   = tree(sigmoid(sum_s part + b))           reduce_tree_kernel (bf16 out)
//   out  = lf @ dT^T                               gemm2_kernel

typedef __bf16 bf16x8 __attribute__((ext_vector_type(8)));
typedef float f32x4 __attribute__((ext_vector_type(4)));
typedef _Float16 f16x8 __attribute__((ext_vector_type(8)));

#define B_DIM 8192
#define F_DIM 4096
#define NI 511
#define NL 512
#define K_DIM 1000
#define KPAD 1024
#define SPLIT 2
#define KCHUNK 2048
#define NT_G1 32            // KCHUNK/64 K-steps per block

#define W_BLKS  1024        // 512*4096 / (256*8)
#define SM_BLKS 512

// RNE fp32->bf16 (prep / tree outputs)
__device__ inline unsigned short f2bf(float f) {
    unsigned int u = __float_as_uint(f);
    return (unsigned short)((u + 0x7FFFu + ((u >> 16) & 1u)) >> 16);
}
__device__ inline unsigned int pk_bf16(float a, float b) {
    return (unsigned int)f2bf(a) | ((unsigned int)f2bf(b) << 16);
}
// cheap round-half-up fp32 pair -> packed bf16x2 (2 adds + 1 perm)
__device__ inline unsigned int pk2_hu(float a, float b) {
    unsigned int ua = __float_as_uint(a) + 0x8000u;
    unsigned int ub = __float_as_uint(b) + 0x8000u;
    return __builtin_amdgcn_perm(ub, ua, 0x07060302u);
}

// async global->LDS, 16 B/lane; LDS dest = wave-uniform base + lane*16
typedef __attribute__((address_space(1))) const unsigned int guint;
typedef __attribute__((address_space(3))) unsigned int luint;
__device__ inline void gload16(const unsigned short* g, unsigned short* l) {
    __builtin_amdgcn_global_load_lds((guint*)g, (luint*)l, 16, 0, 0);
}

// swizzled bf16 fragment load: granule(16B) index ^= row&7  -> conflict-free
__device__ inline bf16x8 ldb(const unsigned short* Lbase, int r, int kb) {
    const int g = (kb >> 3) ^ (r & 7);
    return *(const bf16x8*)&Lbase[r * 64 + g * 8];
}

__device__ inline float waveMax(float v) {
#pragma unroll
    for (int off = 32; off; off >>= 1) v = fmaxf(v, __shfl_down(v, off, 64));
    return v;
}
__device__ inline float waveSum(float v) {
#pragma unroll
    for (int off = 32; off; off >>= 1) v += __shfl_down(v, off, 64);
    return v;
}

// ---------------- prep: W->bf16 (512-row pad), softmax^T ----------------
__global__ __launch_bounds__(256) void prep_kernel(
    const float* __restrict__ W, unsigned short* __restrict__ Wb,
    const float* __restrict__ lp, unsigned short* __restrict__ dT)
{
    __shared__ float sred[8];
    const int bid = blockIdx.x;
    const int tid = threadIdx.x;

    if (bid < W_BLKS) {
        const size_t i = ((size_t)bid * 256 + tid) * 8;
        const int row = (int)(i >> 12);  // /4096
        uint4 h = {0u, 0u, 0u, 0u};
        if (row < NI) {
            const float4 a = *(const float4*)(W + i);
            const float4 b = *(const float4*)(W + i + 4);
            h.x = pk_bf16(a.x, a.y);
            h.y = pk_bf16(a.z, a.w);
            h.z = pk_bf16(b.x, b.y);
            h.w = pk_bf16(b.z, b.w);
        }
        *(uint4*)(Wb + i) = h;
        return;
    }
    // softmax + transpose: dT[n][k] = softmax(leaf_params[k])[n]
    const int k = bid - W_BLKS;
    const int lane = tid & 63;
    const int wave = tid >> 6;
    const float* rowp = lp + (size_t)k * K_DIM;

    float vals[4];
    float mx = -3.0e38f;
#pragma unroll
    for (int c = 0; c < 4; ++c) {
        const int n = tid + c * 256;
        vals[c] = (n < K_DIM) ? rowp[n] : -3.0e38f;
        mx = fmaxf(mx, vals[c]);
    }
    mx = waveMax(mx);
    if (lane == 0) sred[wave] = mx;
    __syncthreads();
    const float gmax = fmaxf(fmaxf(sred[0], sred[1]), fmaxf(sred[2], sred[3]));

    float sum = 0.f;
#pragma unroll
    for (int c = 0; c < 4; ++c) {
        const int n = tid + c * 256;
        const float e = (n < K_DIM) ? __expf(vals[c] - gmax) : 0.f;
        vals[c] = e;
        sum += e;
    }
    sum = waveSum(sum);
    if (lane == 0) sred[4 + wave] = sum;
    __syncthreads();
    const float inv = 1.0f / (sred[4] + sred[5] + sred[6] + sred[7]);
#pragma unroll
    for (int c = 0; c < 4; ++c) {
        const int n = tid + c * 256;
        if (n < K_DIM) dT[(size_t)n * NL + k] = f2bf(vals[c] * inv);
    }
}

// ---------------- GEMM1: part[z] = xs @ Wb^T, counted-vmcnt pipeline ----------------
// grid 512 = 8 xcd x 8 mhi x 2 z x 4 nt; 2 blocks/CU, LDS 80 KB.
// Per iter t: stage A(t) (cvt from regs) -> vmcnt(12)+lgkm(0) -> barrier ->
//             issue B(t+2) gload_lds + A(t+2) reg loads (order pinned) ->
//             compute(t) -> barrier.  vmcnt never drains to 0 in steady state.
// Wait arithmetic: outstanding at the wait = {B(t)4, A(t)8*, B(t+1)4, A(t+1)8}
// oldest-first (sched_barrier(0) fences every region); vmcnt(12) retires B(t).
// (*A(t) already retired by the compiler's own reg-dep wait at the cvt.)
__global__ __launch_bounds__(256, 2) void gemm1_kernel(
    const float* __restrict__ A, const unsigned short* __restrict__ Bb,
    _Float16* __restrict__ part)
{
    __shared__ __align__(16) unsigned short Al[128 * 64];        // 16 KB
    __shared__ __align__(16) unsigned short Bl[4][128 * 64];     // 64 KB, 4 bufs

    const int id = blockIdx.x;
    const int xcd = id & 7;
    const int j = id >> 3;          // 0..63
    const int nt = j & 3;
    const int z = (j >> 2) & 1;
    const int mhi = j >> 3;         // 0..7
    const int m0 = (mhi * 8 + xcd) * 128;
    const int n0 = nt * 128;
    const int kbeg = z * KCHUNK;

    const int tid = threadIdx.x;
    const int lane = tid & 63;
    const int wave = tid >> 6;
    const int wm = (wave >> 1) * 64;
    const int wn = (wave & 1) * 64;
    const int quad = lane >> 4;
    const int l16 = lane & 15;

    // A reg staging: row = wave*4 + (lane>>4) + p*16; q=lane&15 covers cols q*4..+3.
    const int rowA = wave * 4 + (lane >> 4);
    const int q = lane & 15;
    const float* gA = A + (size_t)(m0 + rowA) * F_DIM + kbeg + q * 4;

    // B staging (gload_lds): rows p*32 + wave*8 + (lane>>3); granule = (lane&7)^dr.
    const int drb = lane >> 3;
    const int cb = ((lane & 7) ^ drb) * 8;
    const unsigned short* gB = Bb + (size_t)(n0 + wave * 8 + drb) * F_DIM + kbeg + cb;
    const int lBoff = wave * 8 * 64;

    const f32x4 zero = {0.f, 0.f, 0.f, 0.f};
    f32x4 acc[4][4];
#pragma unroll
    for (int i = 0; i < 4; ++i)
#pragma unroll
        for (int j2 = 0; j2 < 4; ++j2) acc[i][j2] = zero;

    // ---- prologue: B(0),B(1) async; A(0),A(1) to regs (B strictly before A) ----
    f32x4 ab[2][8];
#pragma unroll
    for (int p = 0; p < 4; ++p)
        gload16(gB + (size_t)p * 32 * F_DIM, &Bl[0][lBoff + p * 2048]);
#pragma unroll
    for (int p = 0; p < 4; ++p)
        gload16(gB + 64 + (size_t)p * 32 * F_DIM, &Bl[1][lBoff + p * 2048]);
    __builtin_amdgcn_sched_barrier(0);
#pragma unroll
    for (int p = 0; p < 8; ++p)
        ab[0][p] = *(const f32x4*)(gA + (size_t)p * 16 * F_DIM);
#pragma unroll
    for (int p = 0; p < 8; ++p)
        ab[1][p] = *(const f32x4*)(gA + 64 + (size_t)p * 16 * F_DIM);
    __builtin_amdgcn_sched_barrier(0);

#define G1_ITER(T, DO_ISSUE, WCNT)                                             \
    {                                                                          \
        _Pragma("unroll") for (int p = 0; p < 8; ++p) {                        \
            const int r = rowA + p * 16;                                       \
            uint2 w;                                                           \
            w.x = pk2_hu(ab[(T) & 1][p].x, ab[(T) & 1][p].y);                  \
            w.y = pk2_hu(ab[(T) & 1][p].z, ab[(T) & 1][p].w);                  \
            *(uint2*)&Al[r * 64 + (((q >> 1) ^ (r & 7)) * 8) + (q & 1) * 4] = w;\
        }                                                                      \
        asm volatile("s_waitcnt vmcnt(" #WCNT ") lgkmcnt(0)" ::: "memory");    \
        __builtin_amdgcn_sched_barrier(0);                                     \
        __builtin_amdgcn_s_barrier();                                          \
        __builtin_amdgcn_sched_barrier(0);                                     \
        if (DO_ISSUE) {                                                        \
            _Pragma("unroll") for (int p = 0; p < 4; ++p)                      \
                gload16(gB + (size_t)((T) + 2) * 64 + (size_t)p * 32 * F_DIM,  \
                        &Bl[((T) + 2) & 3][lBoff + p * 2048]);                 \
            __builtin_amdgcn_sched_barrier(0);                                 \
            _Pragma("unroll") for (int p = 0; p < 8; ++p)                      \
                ab[(T) & 1][p] = *(const f32x4*)(gA + (size_t)((T) + 2) * 64   \
                                                 + (size_t)p * 16 * F_DIM);    \
        }                                                                      \
        _Pragma("unroll") for (int kk = 0; kk < 64; kk += 32) {                \
            const int kb = kk + quad * 8;                                      \
            bf16x8 av[4], bv[4];                                               \
            _Pragma("unroll") for (int i = 0; i < 4; ++i)                      \
                av[i] = ldb(Al, wm + i * 16 + l16, kb);                        \
            _Pragma("unroll") for (int j2 = 0; j2 < 4; ++j2)                   \
                bv[j2] = ldb(&Bl[(T) & 3][0], wn + j2 * 16 + l16, kb);         \
            _Pragma("unroll") for (int i = 0; i < 4; ++i)                      \
                _Pragma("unroll") for (int j2 = 0; j2 < 4; ++j2)               \
                    acc[i][j2] = __builtin_amdgcn_mfma_f32_16x16x32_bf16(      \
                        av[i], bv[j2], acc[i][j2], 0, 0, 0);                   \
        }                                                                      \
        __builtin_amdgcn_sched_barrier(0);                                     \
        __builtin_amdgcn_s_barrier();                                          \
        __builtin_amdgcn_sched_barrier(0);                                     \
    }

#pragma unroll 4
    for (int t = 0; t < NT_G1 - 4; ++t) G1_ITER(t, 1, 12);
    G1_ITER(28, 1, 12);
    G1_ITER(29, 1, 12);
    G1_ITER(30, 0, 12);
    G1_ITER(31, 0, 0);
#undef G1_ITER

    _Float16* dst = part + (size_t)z * ((size_t)B_DIM * NL);
#pragma unroll
    for (int i = 0; i < 4; ++i) {
        const int mbase = m0 + wm + i * 16 + quad * 4;
#pragma unroll
        for (int j2 = 0; j2 < 4; ++j2) {
            const int n = n0 + wn + j2 * 16 + l16;
#pragma unroll
            for (int r = 0; r < 4; ++r)
                dst[(size_t)(mbase + r) * NL + n] = (_Float16)acc[i][j2][r];
        }
    }
}

// ---------------- fused reduce(fp16 partials) + bias + sigmoid + tree ----------------
__global__ __launch_bounds__(256) void reduce_tree_kernel(
    const _Float16* __restrict__ part, const float* __restrict__ bvec,
    unsigned short* __restrict__ leafbf)
{
    __shared__ float bsh[NL];
    __shared__ float prow[4][NL];

    const int tid = threadIdx.x;
    bsh[tid] = (tid < NI) ? bvec[tid] : 0.0f;
    const int t2 = tid + 256;
    bsh[t2] = (t2 < NI) ? bvec[t2] : 0.0f;

    const int wave = tid >> 6;
    const int lane = tid & 63;
    const int row = blockIdx.x * 4 + wave;
    const size_t base = (size_t)row * NL + lane * 8;

    float v[8] = {0.f, 0.f, 0.f, 0.f, 0.f, 0.f, 0.f, 0.f};
#pragma unroll
    for (int s = 0; s < SPLIT; ++s) {
        const f16x8 h = *(const f16x8*)(part + (size_t)s * ((size_t)B_DIM * NL) + base);
#pragma unroll
        for (int e = 0; e < 8; ++e) v[e] += (float)h[e];
    }
    __syncthreads();

#pragma unroll
    for (int i = 0; i < 8; ++i) {
        const float x = v[i] + bsh[lane * 8 + i];
        prow[wave][lane * 8 + i] = 1.0f / (1.0f + __expf(-x));
    }
    __syncthreads();

    const float* pr = prow[wave];
    float pre = 1.0f;
    int pnode = 0;
#pragma unroll
    for (int t = 5; t >= 0; --t) {
        const int bit = (lane >> t) & 1;
        const float p = pr[pnode];
        pre *= bit ? p : (1.0f - p);
        pnode = 2 * pnode + 1 + bit;
    }
    unsigned short outs[8];
#pragma unroll
    for (int jj = 0; jj < 8; ++jj) {
        float prob = pre;
        int node = pnode;
#pragma unroll
        for (int t = 2; t >= 0; --t) {
            const int bit = (jj >> t) & 1;
            const float p = pr[node];
            prob *= bit ? p : (1.0f - p);
            node = 2 * node + 1 + bit;
        }
        outs[jj] = f2bf(prob);
    }
    uint4 r;
    r.x = (unsigned int)outs[0] | ((unsigned int)outs[1] << 16);
    r.y = (unsigned int)outs[2] | ((unsigned int)outs[3] << 16);
    r.z = (unsigned int)outs[4] | ((unsigned int)outs[5] << 16);
    r.w = (unsigned int)outs[6] | ((unsigned int)outs[7] << 16);
    *(uint4*)(leafbf + (size_t)row * NL + lane * 8) = r;
}

// ---------------- GEMM2: out = leaf_prob @ dists ----------------
// grid 512 = 8 xcd x 8 mhi x 8 nt; swizzled LDS; masked fp32 stores at n>=1000.
__global__ __launch_bounds__(256) void gemm2_kernel(
    const unsigned short* __restrict__ A, const unsigned short* __restrict__ Bm,
    float* __restrict__ out)
{
    __shared__ __align__(16) unsigned short Al[128 * 64];
    __shared__ __align__(16) unsigned short Bl[128 * 64];

    const int id = blockIdx.x;
    const int xcd = id & 7;
    const int j = id >> 3;
    const int nt = j & 7;
    const int mhi = j >> 3;
    const int m0 = (mhi * 8 + xcd) * 128;
    const int n0 = nt * 128;

    const int tid = threadIdx.x;
    const int lane = tid & 63;
    const int wave = tid >> 6;
    const int wm = (wave >> 1) * 64;
    const int wn = (wave & 1) * 64;
    const int quad = lane >> 4;
    const int l16 = lane & 15;

    const int drb = lane >> 3;
    const int cb = ((lane & 7) ^ drb) * 8;
    const unsigned short* gA = A + (size_t)(m0 + wave * 8 + drb) * NL + cb;
    const unsigned short* gB = Bm + (size_t)(n0 + wave * 8 + drb) * NL + cb;
    unsigned short* lA = &Al[wave * 8 * 64];
    unsigned short* lB = &Bl[wave * 8 * 64];

    const f32x4 zero = {0.f, 0.f, 0.f, 0.f};
    f32x4 acc[4][4];
#pragma unroll
    for (int i = 0; i < 4; ++i)
#pragma unroll
        for (int j2 = 0; j2 < 4; ++j2) acc[i][j2] = zero;

    for (int k0 = 0; k0 < NL; k0 += 64) {
#pragma unroll
        for (int p = 0; p < 4; ++p) {
            gload16(gA + k0 + (size_t)p * 32 * NL, lA + p * 2048);
            gload16(gB + k0 + (size_t)p * 32 * NL, lB + p * 2048);
        }
        __syncthreads();
#pragma unroll
        for (int kk = 0; kk < 64; kk += 32) {
            const int kb = kk + quad * 8;
            bf16x8 av[4], bv[4];
#pragma unroll
            for (int i = 0; i < 4; ++i)
                av[i] = ldb(Al, wm + i * 16 + l16, kb);
#pragma unroll
            for (int j2 = 0; j2 < 4; ++j2)
                bv[j2] = ldb(Bl, wn + j2 * 16 + l16, kb);
#pragma unroll
            for (int i = 0; i < 4; ++i)
#pragma unroll
                for (int j2 = 0; j2 < 4; ++j2)
                    acc[i][j2] = __builtin_amdgcn_mfma_f32_16x16x32_bf16(av[i], bv[j2], acc[i][j2], 0, 0, 0);
        }
        __syncthreads();
    }

#pragma unroll
    for (int i = 0; i < 4; ++i) {
        const int mbase = m0 + wm + i * 16 + quad * 4;
#pragma unroll
        for (int j2 = 0; j2 < 4; ++j2) {
            const int n = n0 + wn + j2 * 16 + l16;
            if (n < K_DIM) {
#pragma unroll
                for (int r = 0; r < 4; ++r)
                    out[(size_t)(mbase + r) * K_DIM + n] = acc[i][j2][r];
            }
        }
    }
}

extern "C" void kernel_launch(void* const* d_in, const int* in_sizes, int n_in,
                              void* d_out, int out_size, void* d_ws, size_t ws_size,
                              hipStream_t stream) {
    const float* xs = (const float*)d_in[0];
    const float* W  = (const float*)d_in[1];
    const float* b  = (const float*)d_in[2];
    const float* lp = (const float*)d_in[3];
    float* out = (float*)d_out;

    const size_t partB = (size_t)B_DIM * NL * 2;   //  8 MiB per slice (fp16)
    const size_t leafB = (size_t)B_DIM * NL * 2;   //  8 MiB
    const size_t dTB   = (size_t)KPAD * NL * 2;    //  1 MiB

    char* ws = (char*)d_ws;
    _Float16* part = (_Float16*)ws;
    unsigned short* leafbf = (unsigned short*)(ws + SPLIT * partB);
    unsigned short* dT = (unsigned short*)(ws + SPLIT * partB + leafB);
    unsigned short* Wb = (unsigned short*)(ws + SPLIT * partB + leafB + dTB);
    (void)ws_size;  // needs ~30 MiB; harness provides 512 MiB

    hipLaunchKernelGGL(prep_kernel, dim3(W_BLKS + SM_BLKS), dim3(256), 0, stream,
                       W, Wb, lp, dT);
    hipLaunchKernelGGL(gemm1_kernel, dim3(8 * 8 * 2 * 4), dim3(256), 0, stream,
                       xs, Wb, part);
    hipLaunchKernelGGL(reduce_tree_kernel, dim3(B_DIM / 4), dim3(256), 0, stream,
                       part, b, leafbf);
    hipLaunchKernelGGL(gemm2_kernel, dim3(8 * 8 * 8), dim3(256), 0, stream,
                       leafbf, dT, out);
}